// Round 6
// baseline (739.712 us; speedup 1.0000x reference)
//
#include <hip/hip_runtime.h>
#include <cstdint>
#include <cstddef>

// ====================================================================
// Attention block: out = softmax(mask? NEG : (QK^T*scale + bias)) V @ Wout^T
// B=8 L=1024 E=1024 H=16 A=64.
// float inputs -> const float*, bool mask -> const int*, output -> float*.
// Structure: k_qkv (GEMM) -> per-head-chunk { k_prep (stream bias+mask ->
// bf16 C), k_attn (flash, reads C) } -> k_out (GEMM).
// Rationale: MFMA-shaped kernels plateau at ~2 TB/s on the scattered
// bias/mask stream (per-CU line-in-flight cap); a dedicated full-occupancy
// streaming kernel reads it at ~6 TB/s and halves the bytes (f32+i32 ->
// bf16). Chunking keeps C L3-resident for the attn pass.
// ====================================================================

typedef __bf16 bf16;
typedef __attribute__((ext_vector_type(8))) __bf16 bf16x8;
typedef __attribute__((ext_vector_type(4))) __bf16 bf16x4;
typedef __attribute__((ext_vector_type(2))) __bf16 bf16x2;
typedef __attribute__((ext_vector_type(4))) float f32x4;
typedef __attribute__((ext_vector_type(4))) int i32x4;

#define MFMA_BF16(a, b, c) __builtin_amdgcn_mfma_f32_16x16x32_bf16(a, b, c, 0, 0, 0)

static constexpr float SCALE_ = 0.125f;        // 64^-0.5
static constexpr float NEGC  = -1.0e30f;       // finite in bf16; exp(NEGC-m)==0

__device__ __forceinline__ void gload_lds16(const bf16* g, bf16* l) {
  __builtin_amdgcn_global_load_lds((const __attribute__((address_space(1))) void*)g,
                                   (__attribute__((address_space(3))) void*)l,
                                   16, 0, 0);
}

__device__ __forceinline__ bf16x8 cvt8(const float* p) {
  f32x4 a = *(const f32x4*)p;
  f32x4 b = *(const f32x4*)(p + 4);
  bf16x8 r = {(bf16)a[0], (bf16)a[1], (bf16)a[2], (bf16)a[3],
              (bf16)b[0], (bf16)b[1], (bf16)b[2], (bf16)b[3]};
  return r;
}

// --------------------------------------------------------------------
// Kernel 0: bias/mask fuse stream. C[i] = mask[i] ? NEGC : bias[i] (bf16).
// Pure stream: 8 elems/thread/iter, grid-stride, minimal VGPR.
// --------------------------------------------------------------------
__global__ __launch_bounds__(256) void k_prep(const float* __restrict__ bias,
                                              const int* __restrict__ mask,
                                              bf16* __restrict__ C, size_t n) {
  size_t i = ((size_t)blockIdx.x * 256 + threadIdx.x) * 8;
  const size_t stride = (size_t)gridDim.x * 256 * 8;
  for (; i < n; i += stride) {
    f32x4 b0 = *(const f32x4*)(bias + i);
    f32x4 b1 = *(const f32x4*)(bias + i + 4);
    i32x4 m0 = *(const i32x4*)(mask + i);
    i32x4 m1 = *(const i32x4*)(mask + i + 4);
    bf16x8 c;
#pragma unroll
    for (int j = 0; j < 4; ++j) c[j] = (bf16)(m0[j] ? NEGC : b0[j]);
#pragma unroll
    for (int j = 0; j < 4; ++j) c[4 + j] = (bf16)(m1[j] ? NEGC : b1[j]);
    *(bf16x8*)(C + i) = c;
  }
}

// --------------------------------------------------------------------
// Kernel 1: QKV projection.  C[8192,3072] = X[8192,1024] @ W[3072,1024]^T
// --------------------------------------------------------------------
__global__ __launch_bounds__(256) void k_qkv(const float* __restrict__ X,
                                             const float* __restrict__ W,
                                             bf16* __restrict__ Q,
                                             bf16* __restrict__ Kc,
                                             bf16* __restrict__ Vt) {
  constexpr int K = 1024;
  __shared__ __align__(16) bf16 As[128 * 64];
  __shared__ __align__(16) bf16 Bs[128 * 64];
  const int t = threadIdx.x;
  const int lane = t & 63, w = t >> 6;
  const int wr = w >> 1, wc = w & 1;
  const int li = lane & 15, g = lane >> 4;
  const int m0 = (blockIdx.x & 63) * 128;   // 64 m-tiles
  const int n0 = (blockIdx.x >> 6) * 128;   // 24 n-tiles

  f32x4 acc[4][4] = {};

  for (int kt = 0; kt < K; kt += 64) {
#pragma unroll
    for (int it = 0; it < 4; ++it) {
      int c = it * 256 + t;               // 0..1023, 8 bf16 elems each
      int row = c >> 3, col = (c & 7) << 3;
      *(bf16x8*)(As + c * 8) = cvt8(X + (size_t)(m0 + row) * K + kt + col);
      *(bf16x8*)(Bs + c * 8) = cvt8(W + (size_t)(n0 + row) * K + kt + col);
    }
    __syncthreads();
#pragma unroll
    for (int kk = 0; kk < 2; ++kk) {
      bf16x8 af[4], bfr[4];
#pragma unroll
      for (int i = 0; i < 4; ++i)
        af[i] = *(const bf16x8*)(As + (wr * 64 + i * 16 + li) * 64 + kk * 32 + g * 8);
#pragma unroll
      for (int j = 0; j < 4; ++j)
        bfr[j] = *(const bf16x8*)(Bs + (wc * 64 + j * 16 + li) * 64 + kk * 32 + g * 8);
#pragma unroll
      for (int i = 0; i < 4; ++i)
#pragma unroll
        for (int j = 0; j < 4; ++j)
          acc[i][j] = MFMA_BF16(af[i], bfr[j], acc[i][j]);
    }
    __syncthreads();
  }

#pragma unroll
  for (int i = 0; i < 4; ++i) {
#pragma unroll
    for (int j = 0; j < 4; ++j) {
      int col = n0 + wc * 64 + j * 16 + li;
      int h = col / 192, r = col % 192;
#pragma unroll
      for (int rg = 0; rg < 4; ++rg) {
        int row = m0 + wr * 64 + i * 16 + g * 4 + rg;
        int b = row >> 10, l = row & 1023;
        bf16 v = (bf16)acc[i][j][rg];
        if (r < 64)
          Q[((size_t)((b * 16 + h) * 1024 + l)) * 64 + r] = v;
        else if (r < 128)
          Kc[((size_t)((b * 16 + h) * 1024 + l)) * 64 + (r - 64)] = v;
        else
          Vt[((size_t)((b * 16 + h) * 64 + (r - 128))) * 1024 + l] = v;
      }
    }
  }
}

// --------------------------------------------------------------------
// Kernel 2: flash attention over a chunk of CH heads. Grid CH*16 blocks;
// bh_local = lid & chmask keeps a head's 16 q-tiles on one XCD.
// Per wave: 16 q rows, swapped QK^T:
//   s[kkf][rg] = S[q=q0+li][k = kkt + kkf*16 + g*4 + rg]
// Masked bias comes precombined as bf16 C (bf16x4 loads, prefetched one
// tile ahead). K/V direct loads (L2/L3-resident). No block barriers;
// per-wave parity-double-buffered LDS P transpose (pad-72 rows).
// --------------------------------------------------------------------
__global__ __launch_bounds__(256) void k_attn(const bf16* __restrict__ Q,
                                              const bf16* __restrict__ Kc,
                                              const bf16* __restrict__ Vt,
                                              const bf16* __restrict__ C,
                                              bf16* __restrict__ Vals,
                                              int bh0, int chmask, int chshift) {
  __shared__ __align__(16) bf16 Plds[4][2][16][72];  // per-wave, pad-72 rows
  const int t = threadIdx.x, lane = t & 63, w = t >> 6;
  const int li = lane & 15, g = lane >> 4;
  const int lid = blockIdx.x;
  const int bhl = lid & chmask;
  const int qt = lid >> chshift;
  const int bh = bh0 + bhl;            // b*16+h
  const int b = bh >> 4, h = bh & 15;
  const int q0 = qt * 64 + w * 16;     // wave's 16 q rows

  const bf16* Qbase = Q + ((size_t)bh << 10) * 64;
  const bf16* Kbase = Kc + ((size_t)bh << 10) * 64;
  const bf16* Vbase = Vt + ((size_t)bh << 6) * 1024;
  const bf16* crow  = C + ((size_t)bhl << 20) + (size_t)(q0 + li) * 1024 + g * 4;

  bf16x8 qf[2];
#pragma unroll
  for (int c = 0; c < 2; ++c)
    qf[c] = *(const bf16x8*)(Qbase + (size_t)(q0 + li) * 64 + c * 32 + g * 8);

  f32x4 oacc[4] = {};
  float mrun = NEGC;
  float lrun = 0.f;

  // ---- prologue: tile-0 masked-bias fragment ----
  bf16x4 cA[4];
#pragma unroll
  for (int kkf = 0; kkf < 4; ++kkf)
    cA[kkf] = *(const bf16x4*)(crow + kkf * 16);

  for (int kt6 = 0; kt6 < 16; ++kt6) {
    const int kkt = kt6 * 64;
    const int par = kt6 & 1;
    const bool more = (kt6 < 15);

    // ---- prefetch next tile's C fragment ----
    bf16x4 cN[4];
    if (more) {
#pragma unroll
      for (int kkf = 0; kkf < 4; ++kkf)
        cN[kkf] = *(const bf16x4*)(crow + kkt + 64 + kkf * 16);
    }

    // ---- S^T = K Q^T ----
    f32x4 s[4];
#pragma unroll
    for (int kkf = 0; kkf < 4; ++kkf) {
      f32x4 ss = {0.f, 0.f, 0.f, 0.f};
#pragma unroll
      for (int c = 0; c < 2; ++c) {
        bf16x8 kf = *(const bf16x8*)(Kbase + (size_t)(kkt + kkf * 16 + li) * 64 + c * 32 + g * 8);
        ss = MFMA_BF16(kf, qf[c], ss);
      }
      s[kkf] = ss;
    }

    // ---- scale + masked-bias, tile max ----
    float tmax = NEGC;
#pragma unroll
    for (int kkf = 0; kkf < 4; ++kkf) {
#pragma unroll
      for (int rg = 0; rg < 4; ++rg) {
        float sv = __builtin_fmaf(s[kkf][rg], SCALE_, (float)cA[kkf][rg]);
        s[kkf][rg] = sv;
        tmax = fmaxf(tmax, sv);
      }
    }
    tmax = fmaxf(tmax, __shfl_xor(tmax, 16));
    tmax = fmaxf(tmax, __shfl_xor(tmax, 32));

    float mnew = fmaxf(mrun, tmax);
    float corr = __expf(mrun - mnew);
    float psum = 0.f;

    // ---- P = exp(s - m) -> per-wave LDS (b32 pair writes) ----
#pragma unroll
    for (int kkf = 0; kkf < 4; ++kkf) {
      float p0 = __expf(s[kkf][0] - mnew);
      float p1 = __expf(s[kkf][1] - mnew);
      float p2 = __expf(s[kkf][2] - mnew);
      float p3 = __expf(s[kkf][3] - mnew);
      psum += (p0 + p1) + (p2 + p3);
      bf16x2 pa = {(bf16)p0, (bf16)p1};
      bf16x2 pb = {(bf16)p2, (bf16)p3};
      *(bf16x2*)(&Plds[w][par][li][kkf * 16 + g * 4])     = pa;
      *(bf16x2*)(&Plds[w][par][li][kkf * 16 + g * 4 + 2]) = pb;
    }
    psum += __shfl_xor(psum, 16);
    psum += __shfl_xor(psum, 32);
    lrun = lrun * corr + psum;
    mrun = mnew;

    // ---- rescale O ----
    float cq[4];
#pragma unroll
    for (int rg = 0; rg < 4; ++rg) cq[rg] = __shfl(corr, g * 4 + rg);
#pragma unroll
    for (int af = 0; af < 4; ++af)
#pragma unroll
      for (int rg = 0; rg < 4; ++rg) oacc[af][rg] *= cq[rg];

    // ---- O += P V ----
#pragma unroll
    for (int c = 0; c < 2; ++c) {
      bf16x8 pf = *(const bf16x8*)(&Plds[w][par][li][c * 32 + g * 8]);
#pragma unroll
      for (int af = 0; af < 4; ++af) {
        bf16x8 vf = *(const bf16x8*)(Vbase + (size_t)(af * 16 + li) * 1024 + kkt + c * 32 + g * 8);
        oacc[af] = MFMA_BF16(pf, vf, oacc[af]);
      }
    }

    if (more) {
#pragma unroll
      for (int kkf = 0; kkf < 4; ++kkf) cA[kkf] = cN[kkf];
    }
  }

  float linv[4];
#pragma unroll
  for (int rg = 0; rg < 4; ++rg) linv[rg] = 1.0f / __shfl(lrun, g * 4 + rg);
#pragma unroll
  for (int af = 0; af < 4; ++af) {
#pragma unroll
    for (int rg = 0; rg < 4; ++rg) {
      int q = q0 + g * 4 + rg;
      int col = h * 64 + af * 16 + li;
      Vals[(((size_t)(b * 1024 + q)) << 10) + col] = (bf16)(oacc[af][rg] * linv[rg]);
    }
  }
}

// --------------------------------------------------------------------
// Kernel 2b: fallback attention reading bias/mask directly (R4 path),
// used only if ws_size can't hold the C buffer.
// --------------------------------------------------------------------
__global__ __launch_bounds__(256) void k_attn_direct(const bf16* __restrict__ Q,
                                                     const bf16* __restrict__ Kc,
                                                     const bf16* __restrict__ Vt,
                                                     const float* __restrict__ bias,
                                                     const int* __restrict__ mask,
                                                     bf16* __restrict__ Vals) {
  __shared__ __align__(16) bf16 Plds[4][2][16][72];
  const int t = threadIdx.x, lane = t & 63, w = t >> 6;
  const int li = lane & 15, g = lane >> 4;
  const int lid = blockIdx.x;
  const int bh = lid & 127;
  const int qt = lid >> 7;
  const int b = bh >> 4, h = bh & 15;
  const int q0 = qt * 64 + w * 16;

  const bf16* Qbase = Q + ((size_t)bh << 10) * 64;
  const bf16* Kbase = Kc + ((size_t)bh << 10) * 64;
  const bf16* Vbase = Vt + ((size_t)bh << 6) * 1024;
  const float* brow = bias + ((size_t)bh << 20) + (size_t)(q0 + li) * 1024 + g * 4;
  const int*   mrow = mask + ((size_t)bh << 20) + (size_t)(q0 + li) * 1024 + g * 4;

  bf16x8 qf[2];
#pragma unroll
  for (int c = 0; c < 2; ++c)
    qf[c] = *(const bf16x8*)(Qbase + (size_t)(q0 + li) * 64 + c * 32 + g * 8);

  f32x4 oacc[4] = {};
  float mrun = NEGC;
  float lrun = 0.f;

  f32x4 b4[4];
  i32x4 m4[4];
#pragma unroll
  for (int kkf = 0; kkf < 4; ++kkf) {
    b4[kkf] = *(const f32x4*)(brow + kkf * 16);
    m4[kkf] = *(const i32x4*)(mrow + kkf * 16);
  }

  for (int kt6 = 0; kt6 < 16; ++kt6) {
    const int kkt = kt6 * 64;
    const int par = kt6 & 1;

    f32x4 c4[4];
#pragma unroll
    for (int kkf = 0; kkf < 4; ++kkf)
#pragma unroll
      for (int rg = 0; rg < 4; ++rg)
        c4[kkf][rg] = m4[kkf][rg] ? NEGC : b4[kkf][rg];

    if (kt6 < 15) {
#pragma unroll
      for (int kkf = 0; kkf < 4; ++kkf) {
        b4[kkf] = *(const f32x4*)(brow + kkt + 64 + kkf * 16);
        m4[kkf] = *(const i32x4*)(mrow + kkt + 64 + kkf * 16);
      }
    }

    f32x4 s[4];
#pragma unroll
    for (int kkf = 0; kkf < 4; ++kkf) {
      f32x4 ss = {0.f, 0.f, 0.f, 0.f};
#pragma unroll
      for (int c = 0; c < 2; ++c) {
        bf16x8 kf = *(const bf16x8*)(Kbase + (size_t)(kkt + kkf * 16 + li) * 64 + c * 32 + g * 8);
        ss = MFMA_BF16(kf, qf[c], ss);
      }
      s[kkf] = ss;
    }

    float tmax = NEGC;
#pragma unroll
    for (int kkf = 0; kkf < 4; ++kkf) {
#pragma unroll
      for (int rg = 0; rg < 4; ++rg) {
        float sv = __builtin_fmaf(s[kkf][rg], SCALE_, c4[kkf][rg]);
        s[kkf][rg] = sv;
        tmax = fmaxf(tmax, sv);
      }
    }
    tmax = fmaxf(tmax, __shfl_xor(tmax, 16));
    tmax = fmaxf(tmax, __shfl_xor(tmax, 32));
    float mnew = fmaxf(mrun, tmax);
    float corr = __expf(mrun - mnew);
    float psum = 0.f;
#pragma unroll
    for (int kkf = 0; kkf < 4; ++kkf) {
      float p0 = __expf(s[kkf][0] - mnew);
      float p1 = __expf(s[kkf][1] - mnew);
      float p2 = __expf(s[kkf][2] - mnew);
      float p3 = __expf(s[kkf][3] - mnew);
      psum += (p0 + p1) + (p2 + p3);
      bf16x2 pa = {(bf16)p0, (bf16)p1};
      bf16x2 pb = {(bf16)p2, (bf16)p3};
      *(bf16x2*)(&Plds[w][par][li][kkf * 16 + g * 4])     = pa;
      *(bf16x2*)(&Plds[w][par][li][kkf * 16 + g * 4 + 2]) = pb;
    }
    psum += __shfl_xor(psum, 16);
    psum += __shfl_xor(psum, 32);
    lrun = lrun * corr + psum;
    mrun = mnew;

    float cq[4];
#pragma unroll
    for (int rg = 0; rg < 4; ++rg) cq[rg] = __shfl(corr, g * 4 + rg);
#pragma unroll
    for (int af = 0; af < 4; ++af)
#pragma unroll
      for (int rg = 0; rg < 4; ++rg) oacc[af][rg] *= cq[rg];

#pragma unroll
    for (int c = 0; c < 2; ++c) {
      bf16x8 pf = *(const bf16x8*)(&Plds[w][par][li][c * 32 + g * 8]);
#pragma unroll
      for (int af = 0; af < 4; ++af) {
        bf16x8 vf = *(const bf16x8*)(Vbase + (size_t)(af * 16 + li) * 1024 + kkt + c * 32 + g * 8);
        oacc[af] = MFMA_BF16(pf, vf, oacc[af]);
      }
    }
  }

  float linv[4];
#pragma unroll
  for (int rg = 0; rg < 4; ++rg) linv[rg] = 1.0f / __shfl(lrun, g * 4 + rg);
#pragma unroll
  for (int af = 0; af < 4; ++af) {
#pragma unroll
    for (int rg = 0; rg < 4; ++rg) {
      int q = q0 + g * 4 + rg;
      int col = h * 64 + af * 16 + li;
      Vals[(((size_t)(b * 1024 + q)) << 10) + col] = (bf16)(oacc[af][rg] * linv[rg]);
    }
  }
}

// --------------------------------------------------------------------
// Kernel 3: output projection. out[8192,1024] = Vals @ Wout[1024,1024]^T
// --------------------------------------------------------------------
__global__ __launch_bounds__(256) void k_out(const bf16* __restrict__ X,
                                             const float* __restrict__ W,
                                             float* __restrict__ Out) {
  constexpr int K = 1024;
  __shared__ __align__(16) bf16 As[128 * 64];
  __shared__ __align__(16) bf16 Bs[128 * 64];
  const int t = threadIdx.x;
  const int lane = t & 63, w = t >> 6;
  const int wr = w >> 1, wc = w & 1;
  const int li = lane & 15, g = lane >> 4;
  const int m0 = (blockIdx.x & 63) * 128;   // 64 m-tiles
  const int n0 = (blockIdx.x >> 6) * 128;   // 8 n-tiles

  f32x4 acc[4][4] = {};

  for (int kt = 0; kt < K; kt += 64) {
#pragma unroll
    for (int it = 0; it < 4; ++it) {
      int c = it * 256 + t;
      int row = c >> 3, col = (c & 7) << 3;
      gload_lds16(X + (size_t)(m0 + row) * K + kt + col, As + c * 8);
      *(bf16x8*)(Bs + c * 8) = cvt8(W + (size_t)(n0 + row) * K + kt + col);
    }
    __syncthreads();
#pragma unroll
    for (int kk = 0; kk < 2; ++kk) {
      bf16x8 af[4], bfr[4];
#pragma unroll
      for (int i = 0; i < 4; ++i)
        af[i] = *(const bf16x8*)(As + (wr * 64 + i * 16 + li) * 64 + kk * 32 + g * 8);
#pragma unroll
      for (int j = 0; j < 4; ++j)
        bfr[j] = *(const bf16x8*)(Bs + (wc * 64 + j * 16 + li) * 64 + kk * 32 + g * 8);
#pragma unroll
      for (int i = 0; i < 4; ++i)
#pragma unroll
        for (int j = 0; j < 4; ++j)
          acc[i][j] = MFMA_BF16(af[i], bfr[j], acc[i][j]);
    }
    __syncthreads();
  }

#pragma unroll
  for (int i = 0; i < 4; ++i) {
#pragma unroll
    for (int j = 0; j < 4; ++j) {
      int col = n0 + wc * 64 + j * 16 + li;
#pragma unroll
      for (int rg = 0; rg < 4; ++rg) {
        int row = m0 + wr * 64 + i * 16 + g * 4 + rg;
        Out[((size_t)row << 10) + col] = acc[i][j][rg];
      }
    }
  }
}

// --------------------------------------------------------------------
extern "C" void kernel_launch(void* const* d_in, const int* in_sizes, int n_in,
                              void* d_out, int out_size, void* d_ws, size_t ws_size,
                              hipStream_t stream) {
  const float* emb  = (const float*)d_in[0];
  const int*   mask = (const int*)d_in[1];
  const float* bias = (const float*)d_in[2];
  const float* Wqkv = (const float*)d_in[3];
  const float* Wout = (const float*)d_in[4];
  float* out = (float*)d_out;

  const size_t HEADS_ELEMS = (size_t)8 * 16 * 1024 * 64;  // 8.39M elems
  bf16* Q    = (bf16*)d_ws;
  bf16* Kc   = Q + HEADS_ELEMS;
  bf16* Vt   = Kc + HEADS_ELEMS;
  bf16* Vals = Vt + HEADS_ELEMS;
  const size_t used = 4 * HEADS_ELEMS * sizeof(bf16);  // 67,108,864 B

  // pick head-chunk size CH (heads per prep+attn pair); C needs CH*2 MiB
  int CH = 0;
  for (int c = 128; c >= 8; c >>= 1)
    if (used + (size_t)c * 2097152 <= ws_size) { CH = c; break; }

  k_qkv<<<dim3(64 * 24), 256, 0, stream>>>(emb, Wqkv, Q, Kc, Vt);

  if (CH) {
    bf16* C = (bf16*)((char*)d_ws + used);
    int chshift = __builtin_ctz((unsigned)CH);
    for (int bh0 = 0; bh0 < 128; bh0 += CH) {
      k_prep<<<dim3(2048), 256, 0, stream>>>(bias + ((size_t)bh0 << 20),
                                             mask + ((size_t)bh0 << 20),
                                             C, (size_t)CH << 20);
      k_attn<<<dim3(CH * 16), 256, 0, stream>>>(Q, Kc, Vt, C, Vals,
                                                bh0, CH - 1, chshift);
    }
  } else {
    k_attn_direct<<<dim3(2048), 256, 0, stream>>>(Q, Kc, Vt, bias, mask, Vals);
  }

  k_out<<<dim3(64 * 8), 256, 0, stream>>>(Vals, Wout, out);
}

// Round 7
// 673.694 us; speedup vs baseline: 1.0980x; 1.0980x over previous
//
#include <hip/hip_runtime.h>
#include <cstdint>
#include <cstddef>

// ====================================================================
// Attention block: out = softmax(mask? NEG : (QK^T*scale + bias)) V @ Wout^T
// B=8 L=1024 E=1024 H=16 A=64.
// float inputs -> const float*, bool mask -> const int*, output -> float*.
// k_attn v3: block = 64 q-rows x full k, k-chunks of 128. bias/mask are
// loaded CONTIGUOUSLY (512B spans per row per chunk) into regs, fused to
// bf16 C, staged via double-buffered LDS. One barrier per chunk; next
// chunk's loads issued right after the barrier (hidden under compute).
// MFMA fragment reads come from LDS, not strided global.
// ====================================================================

typedef __bf16 bf16;
typedef __attribute__((ext_vector_type(8))) __bf16 bf16x8;
typedef __attribute__((ext_vector_type(4))) __bf16 bf16x4;
typedef __attribute__((ext_vector_type(2))) __bf16 bf16x2;
typedef __attribute__((ext_vector_type(4))) float f32x4;
typedef __attribute__((ext_vector_type(4))) int i32x4;

#define MFMA_BF16(a, b, c) __builtin_amdgcn_mfma_f32_16x16x32_bf16(a, b, c, 0, 0, 0)

static constexpr float SCALE_ = 0.125f;        // 64^-0.5
static constexpr float NEGC  = -1.0e30f;       // finite in bf16; exp() -> 0

__device__ __forceinline__ void gload_lds16(const bf16* g, bf16* l) {
  __builtin_amdgcn_global_load_lds((const __attribute__((address_space(1))) void*)g,
                                   (__attribute__((address_space(3))) void*)l,
                                   16, 0, 0);
}

__device__ __forceinline__ bf16x8 cvt8(const float* p) {
  f32x4 a = *(const f32x4*)p;
  f32x4 b = *(const f32x4*)(p + 4);
  bf16x8 r = {(bf16)a[0], (bf16)a[1], (bf16)a[2], (bf16)a[3],
              (bf16)b[0], (bf16)b[1], (bf16)b[2], (bf16)b[3]};
  return r;
}

// --------------------------------------------------------------------
// Kernel 1: QKV projection.  C[8192,3072] = X[8192,1024] @ W[3072,1024]^T
// --------------------------------------------------------------------
__global__ __launch_bounds__(256) void k_qkv(const float* __restrict__ X,
                                             const float* __restrict__ W,
                                             bf16* __restrict__ Q,
                                             bf16* __restrict__ Kc,
                                             bf16* __restrict__ Vt) {
  constexpr int K = 1024;
  __shared__ __align__(16) bf16 As[128 * 64];
  __shared__ __align__(16) bf16 Bs[128 * 64];
  const int t = threadIdx.x;
  const int lane = t & 63, w = t >> 6;
  const int wr = w >> 1, wc = w & 1;
  const int li = lane & 15, g = lane >> 4;
  const int m0 = (blockIdx.x & 63) * 128;   // 64 m-tiles
  const int n0 = (blockIdx.x >> 6) * 128;   // 24 n-tiles

  f32x4 acc[4][4] = {};

  for (int kt = 0; kt < K; kt += 64) {
#pragma unroll
    for (int it = 0; it < 4; ++it) {
      int c = it * 256 + t;               // 0..1023, 8 bf16 elems each
      int row = c >> 3, col = (c & 7) << 3;
      *(bf16x8*)(As + c * 8) = cvt8(X + (size_t)(m0 + row) * K + kt + col);
      *(bf16x8*)(Bs + c * 8) = cvt8(W + (size_t)(n0 + row) * K + kt + col);
    }
    __syncthreads();
#pragma unroll
    for (int kk = 0; kk < 2; ++kk) {
      bf16x8 af[4], bfr[4];
#pragma unroll
      for (int i = 0; i < 4; ++i)
        af[i] = *(const bf16x8*)(As + (wr * 64 + i * 16 + li) * 64 + kk * 32 + g * 8);
#pragma unroll
      for (int j = 0; j < 4; ++j)
        bfr[j] = *(const bf16x8*)(Bs + (wc * 64 + j * 16 + li) * 64 + kk * 32 + g * 8);
#pragma unroll
      for (int i = 0; i < 4; ++i)
#pragma unroll
        for (int j = 0; j < 4; ++j)
          acc[i][j] = MFMA_BF16(af[i], bfr[j], acc[i][j]);
    }
    __syncthreads();
  }

#pragma unroll
  for (int i = 0; i < 4; ++i) {
#pragma unroll
    for (int j = 0; j < 4; ++j) {
      int col = n0 + wc * 64 + j * 16 + li;
      int h = col / 192, r = col % 192;
#pragma unroll
      for (int rg = 0; rg < 4; ++rg) {
        int row = m0 + wr * 64 + i * 16 + g * 4 + rg;
        int b = row >> 10, l = row & 1023;
        bf16 v = (bf16)acc[i][j][rg];
        if (r < 64)
          Q[((size_t)((b * 16 + h) * 1024 + l)) * 64 + r] = v;
        else if (r < 128)
          Kc[((size_t)((b * 16 + h) * 1024 + l)) * 64 + (r - 64)] = v;
        else
          Vt[((size_t)((b * 16 + h) * 64 + (r - 128))) * 1024 + l] = v;
      }
    }
  }
}

// --------------------------------------------------------------------
// Kernel 2: flash attention, contiguous-staged bias/mask.
// Grid 2048: bh = lid&127 (head's 16 q-blocks land on one XCD), qb = lid>>7.
// Block: 4 waves, 64 q-rows; wave w owns rows q0 = qb*64 + w*16.
// Per k-chunk of 128:
//   [ds_write C chunk (from regs)] [issue next chunk's global loads]
//   [barrier] [2x 64-k MFMA subtiles: QK^T, softmax via C from LDS, PV]
// Swapped QK^T layout: s[kkf][rg] = S[q=q0+li][k = kkt + kkf*16 + g*4 + rg].
// --------------------------------------------------------------------
__global__ __launch_bounds__(256, 3) void k_attn(const bf16* __restrict__ Q,
                                                 const bf16* __restrict__ Kc,
                                                 const bf16* __restrict__ Vt,
                                                 const float* __restrict__ bias,
                                                 const int* __restrict__ mask,
                                                 bf16* __restrict__ Vals) {
  __shared__ __align__(16) bf16 Clds[2][64][132];     // 33.8 KB, dbuf chunks
  __shared__ __align__(16) bf16 Plds[4][2][16][72];   // 18 KB, per-wave
  const int t = threadIdx.x, lane = t & 63, w = t >> 6;
  const int li = lane & 15, g = lane >> 4;
  const int lid = blockIdx.x;
  const int bh = lid & 127;            // b*16+h
  const int qb = lid >> 7;
  const int b = bh >> 4, h = bh & 15;
  const int q0 = qb * 64 + w * 16;     // wave's 16 q rows

  const bf16* Qbase = Q + ((size_t)bh << 10) * 64;
  const bf16* Kbase = Kc + ((size_t)bh << 10) * 64;
  const bf16* Vbase = Vt + ((size_t)bh << 6) * 1024;
  const float* bbase = bias + ((size_t)bh << 20) + (size_t)qb * 64 * 1024;
  const int*   mbase = mask + ((size_t)bh << 20) + (size_t)qb * 64 * 1024;

  bf16x8 qf[2];
#pragma unroll
  for (int c = 0; c < 2; ++c)
    qf[c] = *(const bf16x8*)(Qbase + (size_t)(q0 + li) * 64 + c * 32 + g * 8);

  f32x4 oacc[4] = {};
  float mrun = NEGC;
  float lrun = 0.f;

  // staging registers: 32 bias f32 + 32 mask i32 per thread (one chunk)
  f32x4 breg[8];
  i32x4 mreg[8];
  // prologue: chunk 0 (columns 0..127). flat elem f = i*1024 + t*4 in 64x128
#pragma unroll
  for (int i = 0; i < 8; ++i) {
    int f = i * 1024 + t * 4, r = f >> 7, kk = f & 127;
    breg[i] = *(const f32x4*)(bbase + (size_t)r * 1024 + kk);
    mreg[i] = *(const i32x4*)(mbase + (size_t)r * 1024 + kk);
  }

  for (int c = 0; c < 8; ++c) {
    const int par = c & 1;

    // ---- fuse + ds_write chunk c ----
#pragma unroll
    for (int i = 0; i < 8; ++i) {
      int f = i * 1024 + t * 4, r = f >> 7, kk = f & 127;
      bf16x4 cv = {(bf16)(mreg[i][0] ? NEGC : breg[i][0]),
                   (bf16)(mreg[i][1] ? NEGC : breg[i][1]),
                   (bf16)(mreg[i][2] ? NEGC : breg[i][2]),
                   (bf16)(mreg[i][3] ? NEGC : breg[i][3])};
      *(bf16x4*)(&Clds[par][r][kk]) = cv;
    }
    // ---- issue chunk c+1 loads (arrive during compute phase) ----
    if (c < 7) {
#pragma unroll
      for (int i = 0; i < 8; ++i) {
        int f = i * 1024 + t * 4, r = f >> 7, kk = f & 127;
        breg[i] = *(const f32x4*)(bbase + (size_t)r * 1024 + (c + 1) * 128 + kk);
        mreg[i] = *(const i32x4*)(mbase + (size_t)r * 1024 + (c + 1) * 128 + kk);
      }
    }
    __syncthreads();

    // ---- compute: two 64-k subtiles ----
#pragma unroll
    for (int sub = 0; sub < 2; ++sub) {
      const int kkt = c * 128 + sub * 64;

      // S^T = K Q^T
      f32x4 s[4];
#pragma unroll
      for (int kkf = 0; kkf < 4; ++kkf) {
        f32x4 ss = {0.f, 0.f, 0.f, 0.f};
#pragma unroll
        for (int cc = 0; cc < 2; ++cc) {
          bf16x8 kf = *(const bf16x8*)(Kbase + (size_t)(kkt + kkf * 16 + li) * 64 + cc * 32 + g * 8);
          ss = MFMA_BF16(kf, qf[cc], ss);
        }
        s[kkf] = ss;
      }

      // scale + masked-bias (C from LDS), tile max
      float tmax = NEGC;
#pragma unroll
      for (int kkf = 0; kkf < 4; ++kkf) {
        bf16x4 cf = *(const bf16x4*)(&Clds[par][w * 16 + li][sub * 64 + kkf * 16 + g * 4]);
#pragma unroll
        for (int rg = 0; rg < 4; ++rg) {
          float sv = __builtin_fmaf(s[kkf][rg], SCALE_, (float)cf[rg]);
          s[kkf][rg] = sv;
          tmax = fmaxf(tmax, sv);
        }
      }
      tmax = fmaxf(tmax, __shfl_xor(tmax, 16));
      tmax = fmaxf(tmax, __shfl_xor(tmax, 32));

      float mnew = fmaxf(mrun, tmax);
      float corr = __expf(mrun - mnew);
      float psum = 0.f;

      // P = exp(s - m) -> per-wave LDS
#pragma unroll
      for (int kkf = 0; kkf < 4; ++kkf) {
        float p0 = __expf(s[kkf][0] - mnew);
        float p1 = __expf(s[kkf][1] - mnew);
        float p2 = __expf(s[kkf][2] - mnew);
        float p3 = __expf(s[kkf][3] - mnew);
        psum += (p0 + p1) + (p2 + p3);
        bf16x2 pa = {(bf16)p0, (bf16)p1};
        bf16x2 pb = {(bf16)p2, (bf16)p3};
        *(bf16x2*)(&Plds[w][sub][li][kkf * 16 + g * 4])     = pa;
        *(bf16x2*)(&Plds[w][sub][li][kkf * 16 + g * 4 + 2]) = pb;
      }
      psum += __shfl_xor(psum, 16);
      psum += __shfl_xor(psum, 32);
      lrun = lrun * corr + psum;
      mrun = mnew;

      // rescale O
      float cq[4];
#pragma unroll
      for (int rg = 0; rg < 4; ++rg) cq[rg] = __shfl(corr, g * 4 + rg);
#pragma unroll
      for (int af = 0; af < 4; ++af)
#pragma unroll
        for (int rg = 0; rg < 4; ++rg) oacc[af][rg] *= cq[rg];

      // O += P V
#pragma unroll
      for (int cc = 0; cc < 2; ++cc) {
        bf16x8 pf = *(const bf16x8*)(&Plds[w][sub][li][cc * 32 + g * 8]);
#pragma unroll
        for (int af = 0; af < 4; ++af) {
          bf16x8 vf = *(const bf16x8*)(Vbase + (size_t)(af * 16 + li) * 1024 + kkt + cc * 32 + g * 8);
          oacc[af] = MFMA_BF16(pf, vf, oacc[af]);
        }
      }
    }
  }

  float linv[4];
#pragma unroll
  for (int rg = 0; rg < 4; ++rg) linv[rg] = 1.0f / __shfl(lrun, g * 4 + rg);
#pragma unroll
  for (int af = 0; af < 4; ++af) {
#pragma unroll
    for (int rg = 0; rg < 4; ++rg) {
      int q = q0 + g * 4 + rg;
      int col = h * 64 + af * 16 + li;
      Vals[(((size_t)(b * 1024 + q)) << 10) + col] = (bf16)(oacc[af][rg] * linv[rg]);
    }
  }
}

// --------------------------------------------------------------------
// Kernel 3: output projection. out[8192,1024] = Vals @ Wout[1024,1024]^T
// --------------------------------------------------------------------
__global__ __launch_bounds__(256) void k_out(const bf16* __restrict__ X,
                                             const float* __restrict__ W,
                                             float* __restrict__ Out) {
  constexpr int K = 1024;
  __shared__ __align__(16) bf16 As[128 * 64];
  __shared__ __align__(16) bf16 Bs[128 * 64];
  const int t = threadIdx.x;
  const int lane = t & 63, w = t >> 6;
  const int wr = w >> 1, wc = w & 1;
  const int li = lane & 15, g = lane >> 4;
  const int m0 = (blockIdx.x & 63) * 128;   // 64 m-tiles
  const int n0 = (blockIdx.x >> 6) * 128;   // 8 n-tiles

  f32x4 acc[4][4] = {};

  for (int kt = 0; kt < K; kt += 64) {
#pragma unroll
    for (int it = 0; it < 4; ++it) {
      int c = it * 256 + t;
      int row = c >> 3, col = (c & 7) << 3;
      gload_lds16(X + (size_t)(m0 + row) * K + kt + col, As + c * 8);
      *(bf16x8*)(Bs + c * 8) = cvt8(W + (size_t)(n0 + row) * K + kt + col);
    }
    __syncthreads();
#pragma unroll
    for (int kk = 0; kk < 2; ++kk) {
      bf16x8 af[4], bfr[4];
#pragma unroll
      for (int i = 0; i < 4; ++i)
        af[i] = *(const bf16x8*)(As + (wr * 64 + i * 16 + li) * 64 + kk * 32 + g * 8);
#pragma unroll
      for (int j = 0; j < 4; ++j)
        bfr[j] = *(const bf16x8*)(Bs + (wc * 64 + j * 16 + li) * 64 + kk * 32 + g * 8);
#pragma unroll
      for (int i = 0; i < 4; ++i)
#pragma unroll
        for (int j = 0; j < 4; ++j)
          acc[i][j] = MFMA_BF16(af[i], bfr[j], acc[i][j]);
    }
    __syncthreads();
  }

#pragma unroll
  for (int i = 0; i < 4; ++i) {
#pragma unroll
    for (int j = 0; j < 4; ++j) {
      int col = n0 + wc * 64 + j * 16 + li;
#pragma unroll
      for (int rg = 0; rg < 4; ++rg) {
        int row = m0 + wr * 64 + i * 16 + g * 4 + rg;
        Out[((size_t)row << 10) + col] = acc[i][j][rg];
      }
    }
  }
}

// --------------------------------------------------------------------
extern "C" void kernel_launch(void* const* d_in, const int* in_sizes, int n_in,
                              void* d_out, int out_size, void* d_ws, size_t ws_size,
                              hipStream_t stream) {
  const float* emb  = (const float*)d_in[0];
  const int*   mask = (const int*)d_in[1];
  const float* bias = (const float*)d_in[2];
  const float* Wqkv = (const float*)d_in[3];
  const float* Wout = (const float*)d_in[4];
  float* out = (float*)d_out;

  const size_t HEADS_ELEMS = (size_t)8 * 16 * 1024 * 64;  // 8.39M elems
  bf16* Q    = (bf16*)d_ws;
  bf16* Kc   = Q + HEADS_ELEMS;
  bf16* Vt   = Kc + HEADS_ELEMS;
  bf16* Vals = Vt + HEADS_ELEMS;   // total ~67 MiB of ws

  k_qkv<<<dim3(64 * 24), 256, 0, stream>>>(emb, Wqkv, Q, Kc, Vt);
  k_attn<<<dim3(2048), 256, 0, stream>>>(Q, Kc, Vt, bias, mask, Vals);
  k_out<<<dim3(64 * 8), 256, 0, stream>>>(Vals, Wout, out);
}

// Round 8
// 545.277 us; speedup vs baseline: 1.3566x; 1.2355x over previous
//
#include <hip/hip_runtime.h>
#include <cstdint>
#include <cstddef>

// ====================================================================
// Attention block: out = softmax(mask? NEG : (QK^T*scale + bias)) V @ Wout^T
// B=8 L=1024 E=1024 H=16 A=64.
// float inputs -> const float*, bool mask -> const int*, output -> float*.
// k_attn (R4 structure + k-phase rotation): swapped QK^T (S^T layout),
// float4/int4 bias/mask prefetched one tile ahead, mask folded at consume;
// per-wave parity-double-buffered LDS P transpose; NO barriers.
// NEW: each block sweeps k-chunks starting at rot=(bh+qt)&15 so the grid's
// bias/mask reads spread across all within-row address bands (defeats
// L2/HBM channel camping that pinned every prior variant at ~1.9 TB/s).
// Online softmax is k-order-invariant, so results are unchanged.
// ====================================================================

typedef __bf16 bf16;
typedef __attribute__((ext_vector_type(8))) __bf16 bf16x8;
typedef __attribute__((ext_vector_type(2))) __bf16 bf16x2;
typedef __attribute__((ext_vector_type(4))) float f32x4;
typedef __attribute__((ext_vector_type(4))) int i32x4;

#define MFMA_BF16(a, b, c) __builtin_amdgcn_mfma_f32_16x16x32_bf16(a, b, c, 0, 0, 0)

static constexpr float SCALE_ = 0.125f;                     // 64^-0.5
static constexpr float NEGF  = -3.4028234663852886e38f;     // finfo(f32).min

__device__ __forceinline__ void gload_lds16(const bf16* g, bf16* l) {
  __builtin_amdgcn_global_load_lds((const __attribute__((address_space(1))) void*)g,
                                   (__attribute__((address_space(3))) void*)l,
                                   16, 0, 0);
}

__device__ __forceinline__ bf16x8 cvt8(const float* p) {
  f32x4 a = *(const f32x4*)p;
  f32x4 b = *(const f32x4*)(p + 4);
  bf16x8 r = {(bf16)a[0], (bf16)a[1], (bf16)a[2], (bf16)a[3],
              (bf16)b[0], (bf16)b[1], (bf16)b[2], (bf16)b[3]};
  return r;
}

// --------------------------------------------------------------------
// Kernel 1: QKV projection.  C[8192,3072] = X[8192,1024] @ W[3072,1024]^T
// --------------------------------------------------------------------
__global__ __launch_bounds__(256) void k_qkv(const float* __restrict__ X,
                                             const float* __restrict__ W,
                                             bf16* __restrict__ Q,
                                             bf16* __restrict__ Kc,
                                             bf16* __restrict__ Vt) {
  constexpr int K = 1024;
  __shared__ __align__(16) bf16 As[128 * 64];
  __shared__ __align__(16) bf16 Bs[128 * 64];
  const int t = threadIdx.x;
  const int lane = t & 63, w = t >> 6;
  const int wr = w >> 1, wc = w & 1;
  const int li = lane & 15, g = lane >> 4;
  const int m0 = (blockIdx.x & 63) * 128;   // 64 m-tiles
  const int n0 = (blockIdx.x >> 6) * 128;   // 24 n-tiles

  f32x4 acc[4][4] = {};

  for (int kt = 0; kt < K; kt += 64) {
#pragma unroll
    for (int it = 0; it < 4; ++it) {
      int c = it * 256 + t;               // 0..1023, 8 bf16 elems each
      int row = c >> 3, col = (c & 7) << 3;
      *(bf16x8*)(As + c * 8) = cvt8(X + (size_t)(m0 + row) * K + kt + col);
      *(bf16x8*)(Bs + c * 8) = cvt8(W + (size_t)(n0 + row) * K + kt + col);
    }
    __syncthreads();
#pragma unroll
    for (int kk = 0; kk < 2; ++kk) {
      bf16x8 af[4], bfr[4];
#pragma unroll
      for (int i = 0; i < 4; ++i)
        af[i] = *(const bf16x8*)(As + (wr * 64 + i * 16 + li) * 64 + kk * 32 + g * 8);
#pragma unroll
      for (int j = 0; j < 4; ++j)
        bfr[j] = *(const bf16x8*)(Bs + (wc * 64 + j * 16 + li) * 64 + kk * 32 + g * 8);
#pragma unroll
      for (int i = 0; i < 4; ++i)
#pragma unroll
        for (int j = 0; j < 4; ++j)
          acc[i][j] = MFMA_BF16(af[i], bfr[j], acc[i][j]);
    }
    __syncthreads();
  }

#pragma unroll
  for (int i = 0; i < 4; ++i) {
#pragma unroll
    for (int j = 0; j < 4; ++j) {
      int col = n0 + wc * 64 + j * 16 + li;
      int h = col / 192, r = col % 192;
#pragma unroll
      for (int rg = 0; rg < 4; ++rg) {
        int row = m0 + wr * 64 + i * 16 + g * 4 + rg;
        int b = row >> 10, l = row & 1023;
        bf16 v = (bf16)acc[i][j][rg];
        if (r < 64)
          Q[((size_t)((b * 16 + h) * 1024 + l)) * 64 + r] = v;
        else if (r < 128)
          Kc[((size_t)((b * 16 + h) * 1024 + l)) * 64 + (r - 64)] = v;
        else
          Vt[((size_t)((b * 16 + h) * 64 + (r - 128))) * 1024 + l] = v;
      }
    }
  }
}

// --------------------------------------------------------------------
// Kernel 2: flash attention. Grid 2048: bh = lid&127 (head's q-blocks on
// one XCD), qt = lid>>7. Per wave 16 q rows, swapped QK^T:
//   s[kkf][rg] = S[q=q0+li][k = kkt + kkf*16 + g*4 + rg]
// k-chunks processed in rotated order (rot per block) to decorrelate the
// grid's bias/mask column bands across memory channels.
// --------------------------------------------------------------------
__global__ __launch_bounds__(256) void k_attn(const bf16* __restrict__ Q,
                                              const bf16* __restrict__ Kc,
                                              const bf16* __restrict__ Vt,
                                              const float* __restrict__ bias,
                                              const int* __restrict__ mask,
                                              bf16* __restrict__ Vals) {
  __shared__ __align__(16) bf16 Plds[4][2][16][72];  // per-wave, pad-72 rows
  const int t = threadIdx.x, lane = t & 63, w = t >> 6;
  const int li = lane & 15, g = lane >> 4;
  const int lid = blockIdx.x;
  const int bh = lid & 127;            // b*16+h
  const int qt = lid >> 7;
  const int b = bh >> 4, h = bh & 15;
  const int q0 = qt * 64 + w * 16;     // wave's 16 q rows
  const int rot = (bh + qt) & 15;      // per-block k-phase

  const bf16* Qbase = Q + ((size_t)bh << 10) * 64;
  const bf16* Kbase = Kc + ((size_t)bh << 10) * 64;
  const bf16* Vbase = Vt + ((size_t)bh << 6) * 1024;
  const float* brow = bias + ((size_t)bh << 20) + (size_t)(q0 + li) * 1024 + g * 4;
  const int*   mrow = mask + ((size_t)bh << 20) + (size_t)(q0 + li) * 1024 + g * 4;

  bf16x8 qf[2];
#pragma unroll
  for (int c = 0; c < 2; ++c)
    qf[c] = *(const bf16x8*)(Qbase + (size_t)(q0 + li) * 64 + c * 32 + g * 8);

  f32x4 oacc[4] = {};
  float mrun = NEGF;
  float lrun = 0.f;

  // ---- prologue: issue first chunk's bias/mask loads ----
  f32x4 b4[4];
  i32x4 m4[4];
  {
    const int kkt0 = rot * 64;
#pragma unroll
    for (int kkf = 0; kkf < 4; ++kkf) {
      b4[kkf] = *(const f32x4*)(brow + kkt0 + kkf * 16);
      m4[kkf] = *(const i32x4*)(mrow + kkt0 + kkf * 16);
    }
  }

  for (int i6 = 0; i6 < 16; ++i6) {
    const int kt6 = (i6 + rot) & 15;
    const int kkt = kt6 * 64;
    const int par = i6 & 1;
    const bool more = (i6 < 15);
    const int kktn = (((i6 + 1 + rot) & 15)) * 64;

    // ---- consume prefetched bias/mask: fold mask into bias ----
    f32x4 c4[4];
#pragma unroll
    for (int kkf = 0; kkf < 4; ++kkf)
#pragma unroll
      for (int rg = 0; rg < 4; ++rg)
        c4[kkf][rg] = m4[kkf][rg] ? NEGF : b4[kkf][rg];

    // ---- issue next chunk's bias/mask loads (hidden under QK+softmax+PV) ----
    if (more) {
#pragma unroll
      for (int kkf = 0; kkf < 4; ++kkf) {
        b4[kkf] = *(const f32x4*)(brow + kktn + kkf * 16);
        m4[kkf] = *(const i32x4*)(mrow + kktn + kkf * 16);
      }
    }

    // ---- S^T = K Q^T (per wave: 64k x 16q as 4 fragments) ----
    f32x4 s[4];
#pragma unroll
    for (int kkf = 0; kkf < 4; ++kkf) {
      f32x4 ss = {0.f, 0.f, 0.f, 0.f};
#pragma unroll
      for (int c = 0; c < 2; ++c) {
        bf16x8 kf = *(const bf16x8*)(Kbase + (size_t)(kkt + kkf * 16 + li) * 64 + c * 32 + g * 8);
        ss = MFMA_BF16(kf, qf[c], ss);
      }
      s[kkf] = ss;
    }

    // ---- scale + masked-bias, tile max ----
    float tmax = NEGF;
#pragma unroll
    for (int kkf = 0; kkf < 4; ++kkf) {
#pragma unroll
      for (int rg = 0; rg < 4; ++rg) {
        float sv = __builtin_fmaf(s[kkf][rg], SCALE_, c4[kkf][rg]);
        s[kkf][rg] = sv;
        tmax = fmaxf(tmax, sv);
      }
    }
    tmax = fmaxf(tmax, __shfl_xor(tmax, 16));
    tmax = fmaxf(tmax, __shfl_xor(tmax, 32));

    float mnew = fmaxf(mrun, tmax);
    float corr = __expf(mrun - mnew);   // NEG-NEG=0 -> 1; NEG-real -> 0
    float psum = 0.f;

    // ---- P = exp(s - m): pack pairs, b32 LDS writes ----
#pragma unroll
    for (int kkf = 0; kkf < 4; ++kkf) {
      float p0 = __expf(s[kkf][0] - mnew);
      float p1 = __expf(s[kkf][1] - mnew);
      float p2 = __expf(s[kkf][2] - mnew);
      float p3 = __expf(s[kkf][3] - mnew);
      psum += (p0 + p1) + (p2 + p3);
      bf16x2 pa = {(bf16)p0, (bf16)p1};
      bf16x2 pb = {(bf16)p2, (bf16)p3};
      *(bf16x2*)(&Plds[w][par][li][kkf * 16 + g * 4])     = pa;
      *(bf16x2*)(&Plds[w][par][li][kkf * 16 + g * 4 + 2]) = pb;
    }
    psum += __shfl_xor(psum, 16);
    psum += __shfl_xor(psum, 32);
    lrun = lrun * corr + psum;
    mrun = mnew;

    // ---- rescale O by per-row corr ----
    float cq[4];
#pragma unroll
    for (int rg = 0; rg < 4; ++rg) cq[rg] = __shfl(corr, g * 4 + rg);
#pragma unroll
    for (int af = 0; af < 4; ++af)
#pragma unroll
      for (int rg = 0; rg < 4; ++rg) oacc[af][rg] *= cq[rg];

    // ---- O += P V ----
#pragma unroll
    for (int c = 0; c < 2; ++c) {
      bf16x8 pf = *(const bf16x8*)(&Plds[w][par][li][c * 32 + g * 8]);
#pragma unroll
      for (int af = 0; af < 4; ++af) {
        bf16x8 vf = *(const bf16x8*)(Vbase + (size_t)(af * 16 + li) * 1024 + kkt + c * 32 + g * 8);
        oacc[af] = MFMA_BF16(pf, vf, oacc[af]);
      }
    }
  }

  float linv[4];
#pragma unroll
  for (int rg = 0; rg < 4; ++rg) linv[rg] = 1.0f / __shfl(lrun, g * 4 + rg);
#pragma unroll
  for (int af = 0; af < 4; ++af) {
#pragma unroll
    for (int rg = 0; rg < 4; ++rg) {
      int q = q0 + g * 4 + rg;
      int col = h * 64 + af * 16 + li;
      Vals[(((size_t)(b * 1024 + q)) << 10) + col] = (bf16)(oacc[af][rg] * linv[rg]);
    }
  }
}

// --------------------------------------------------------------------
// Kernel 3: output projection. out[8192,1024] = Vals @ Wout[1024,1024]^T
// --------------------------------------------------------------------
__global__ __launch_bounds__(256) void k_out(const bf16* __restrict__ X,
                                             const float* __restrict__ W,
                                             float* __restrict__ Out) {
  constexpr int K = 1024;
  __shared__ __align__(16) bf16 As[128 * 64];
  __shared__ __align__(16) bf16 Bs[128 * 64];
  const int t = threadIdx.x;
  const int lane = t & 63, w = t >> 6;
  const int wr = w >> 1, wc = w & 1;
  const int li = lane & 15, g = lane >> 4;
  const int m0 = (blockIdx.x & 63) * 128;   // 64 m-tiles
  const int n0 = (blockIdx.x >> 6) * 128;   // 8 n-tiles

  f32x4 acc[4][4] = {};

  for (int kt = 0; kt < K; kt += 64) {
#pragma unroll
    for (int it = 0; it < 4; ++it) {
      int c = it * 256 + t;
      int row = c >> 3, col = (c & 7) << 3;
      gload_lds16(X + (size_t)(m0 + row) * K + kt + col, As + c * 8);
      *(bf16x8*)(Bs + c * 8) = cvt8(W + (size_t)(n0 + row) * K + kt + col);
    }
    __syncthreads();
#pragma unroll
    for (int kk = 0; kk < 2; ++kk) {
      bf16x8 af[4], bfr[4];
#pragma unroll
      for (int i = 0; i < 4; ++i)
        af[i] = *(const bf16x8*)(As + (wr * 64 + i * 16 + li) * 64 + kk * 32 + g * 8);
#pragma unroll
      for (int j = 0; j < 4; ++j)
        bfr[j] = *(const bf16x8*)(Bs + (wc * 64 + j * 16 + li) * 64 + kk * 32 + g * 8);
#pragma unroll
      for (int i = 0; i < 4; ++i)
#pragma unroll
        for (int j = 0; j < 4; ++j)
          acc[i][j] = MFMA_BF16(af[i], bfr[j], acc[i][j]);
    }
    __syncthreads();
  }

#pragma unroll
  for (int i = 0; i < 4; ++i) {
#pragma unroll
    for (int j = 0; j < 4; ++j) {
      int col = n0 + wc * 64 + j * 16 + li;
#pragma unroll
      for (int rg = 0; rg < 4; ++rg) {
        int row = m0 + wr * 64 + i * 16 + g * 4 + rg;
        Out[((size_t)row << 10) + col] = acc[i][j][rg];
      }
    }
  }
}

// --------------------------------------------------------------------
extern "C" void kernel_launch(void* const* d_in, const int* in_sizes, int n_in,
                              void* d_out, int out_size, void* d_ws, size_t ws_size,
                              hipStream_t stream) {
  const float* emb  = (const float*)d_in[0];
  const int*   mask = (const int*)d_in[1];
  const float* bias = (const float*)d_in[2];
  const float* Wqkv = (const float*)d_in[3];
  const float* Wout = (const float*)d_in[4];
  float* out = (float*)d_out;

  const size_t HEADS_ELEMS = (size_t)8 * 16 * 1024 * 64;  // 8.39M elems
  bf16* Q    = (bf16*)d_ws;
  bf16* Kc   = Q + HEADS_ELEMS;
  bf16* Vt   = Kc + HEADS_ELEMS;
  bf16* Vals = Vt + HEADS_ELEMS;   // total ~67 MiB of ws

  k_qkv<<<dim3(64 * 24), 256, 0, stream>>>(emb, Wqkv, Q, Kc, Vt);
  k_attn<<<dim3(2048), 256, 0, stream>>>(Q, Kc, Vt, bias, mask, Vals);
  k_out<<<dim3(64 * 8), 256, 0, stream>>>(Vals, Wout, out);
}